// Round 2
// baseline (502.459 us; speedup 1.0000x reference)
//
#include <hip/hip_runtime.h>
#include <stdint.h>
#include <stddef.h>

typedef __attribute__((ext_vector_type(4))) int i32x4;
typedef __attribute__((ext_vector_type(16))) int i32x16;

#define BM 128
#define BN 128
#define BK 64

// ---------------- async global -> LDS (16B per lane) ----------------
__device__ __forceinline__ void gload_lds16(const void* g, void* l) {
    __builtin_amdgcn_global_load_lds(
        (const __attribute__((address_space(1))) void*)g,
        (__attribute__((address_space(3))) void*)l,
        16, 0, 0);
}

// ---------------- butterfly wave reductions (result in ALL lanes) ----------------
__device__ __forceinline__ float waveMaxF(float v) {
#pragma unroll
    for (int o = 32; o > 0; o >>= 1) v = fmaxf(v, __shfl_xor(v, o, 64));
    return v;
}
__device__ __forceinline__ float waveMinF(float v) {
#pragma unroll
    for (int o = 32; o > 0; o >>= 1) v = fminf(v, __shfl_xor(v, o, 64));
    return v;
}
__device__ __forceinline__ int waveSumI(int v) {
#pragma unroll
    for (int o = 32; o > 0; o >>= 1) v += __shfl_xor(v, o, 64);
    return v;
}

// ---------------- fused quantization: one WAVE per row, no barriers ----------------
// blocks [0, NBW): weight rows (4 per block). blocks [NBW, NBW+NBA): token rows.
// Weight:  symmetric int8, rscale[n] = absmax/127, rsum[n] = sum(Wq[n,:]).
// Activ.:  asymmetric uint8 stored as (Xq-128) signed; azp[m] = 128 - zp.
__global__ void __launch_bounds__(256) quant_kernel(
    const float* __restrict__ W, const float* __restrict__ X,
    int8_t* __restrict__ Wq, int8_t* __restrict__ Xq,
    float* __restrict__ rscale, int* __restrict__ rsum,
    float* __restrict__ cscale, int* __restrict__ azp,
    int K, int N, int M, int NBW) {
    const int wave = threadIdx.x >> 6;
    const int lane = threadIdx.x & 63;
    const int K4 = K >> 2;

    if ((int)blockIdx.x < NBW) {
        const int n = blockIdx.x * 4 + wave;
        if (n >= N) return;
        const float4* src = (const float4*)(W + (size_t)n * K);

        float amax = 0.f;
        for (int i = lane; i < K4; i += 64) {
            float4 f = src[i];
            amax = fmaxf(amax, fmaxf(fmaxf(fabsf(f.x), fabsf(f.y)),
                                     fmaxf(fabsf(f.z), fabsf(f.w))));
        }
        amax = waveMaxF(amax);
        const float scale = (amax > 0.f) ? (amax / 127.0f) : 1.0f;  // one uniform div
        const float inv = 1.0f / scale;                              // one uniform div

        int lsum = 0;
        char4* out = (char4*)(Wq + (size_t)n * K);
        for (int i = lane; i < K4; i += 64) {
            float4 f = src[i];
            int i0 = (int)fminf(fmaxf(rintf(f.x * inv), -127.f), 127.f);
            int i1 = (int)fminf(fmaxf(rintf(f.y * inv), -127.f), 127.f);
            int i2 = (int)fminf(fmaxf(rintf(f.z * inv), -127.f), 127.f);
            int i3 = (int)fminf(fmaxf(rintf(f.w * inv), -127.f), 127.f);
            lsum += i0 + i1 + i2 + i3;
            char4 c;
            c.x = (signed char)i0; c.y = (signed char)i1;
            c.z = (signed char)i2; c.w = (signed char)i3;
            out[i] = c;
        }
        lsum = waveSumI(lsum);
        if (lane == 0) { rsum[n] = lsum; rscale[n] = scale; }
    } else {
        const int m = ((int)blockIdx.x - NBW) * 4 + wave;
        if (m >= M) return;
        const float4* src = (const float4*)(X + (size_t)m * K);

        float vmin = 3.402823466e38f, vmax = -3.402823466e38f;
        for (int i = lane; i < K4; i += 64) {
            float4 f = src[i];
            vmin = fminf(vmin, fminf(fminf(f.x, f.y), fminf(f.z, f.w)));
            vmax = fmaxf(vmax, fmaxf(fmaxf(f.x, f.y), fmaxf(f.z, f.w)));
        }
        vmin = waveMinF(vmin);
        vmax = waveMaxF(vmax);
        const float rng = vmax - vmin;
        const float scale = (rng > 0.f) ? (rng / 255.0f) : 1.0f;  // uniform div
        const float zp = rintf(-vmin / scale);                     // uniform div
        const float inv = 1.0f / scale;                            // uniform div

        char4* out = (char4*)(Xq + (size_t)m * K);
        for (int i = lane; i < K4; i += 64) {
            float4 f = src[i];
            int q0 = (int)fminf(fmaxf(rintf(f.x * inv) + zp, 0.f), 255.f) - 128;
            int q1 = (int)fminf(fmaxf(rintf(f.y * inv) + zp, 0.f), 255.f) - 128;
            int q2 = (int)fminf(fmaxf(rintf(f.z * inv) + zp, 0.f), 255.f) - 128;
            int q3 = (int)fminf(fmaxf(rintf(f.w * inv) + zp, 0.f), 255.f) - 128;
            char4 c;
            c.x = (signed char)q0; c.y = (signed char)q1;
            c.z = (signed char)q2; c.w = (signed char)q3;
            out[i] = c;
        }
        if (lane == 0) { cscale[m] = scale; azp[m] = 128 - (int)zp; }
    }
}

// ---------------- int8 GEMM, 32x32x32 MFMA, XOR-swizzled LDS ----------------
// Y[m,n] = (dot_i8(A[m],B[n]) + azp[m]*rsum[n]) * cs[m]*rs[n] + bias[n]
// 128x128 tile, 4 waves; each wave: 64x64 = 2x2 tiles of 32x32, acc i32x16 each.
// LDS swizzle: 16B chunk at physical column p of row r holds logical chunk p^(r&3);
// inverted on the GLOBAL address during staging (LDS side of global_load_lds is
// lane-contiguous and cannot scatter).
__global__ void __launch_bounds__(256) gemm_i8_kernel(
    const int8_t* __restrict__ A, const int8_t* __restrict__ B,
    float* __restrict__ Y,
    const float* __restrict__ cs, const int* __restrict__ azp,
    const float* __restrict__ rs, const int* __restrict__ rsum,
    const float* __restrict__ bias, int M, int N, int K) {
    __shared__ int8_t As[BM * BK];  // 8 KB
    __shared__ int8_t Bs[BN * BK];  // 8 KB

    const int tid = threadIdx.x;
    const int lane = tid & 63;
    const int wave = tid >> 6;
    const int wm = wave & 1;
    const int wn = wave >> 1;
    const int ml = lane & 31;   // m (A) / n (B) within a 32-tile
    const int kh = lane >> 5;   // k-half selector within a 32-wide k step

    const int bm = blockIdx.x * BM;
    const int bn = blockIdx.y * BN;

    const int8_t* Ag = A + (size_t)bm * K;
    const int8_t* Bg = B + (size_t)bn * K;

    // staging: thread t -> row t/4, physical chunk t&3 (LDS dest = tid*16),
    // global chunk = (t&3) ^ (row&3). Rows r and r+64 share (r&3) -> same swizzle.
    const int srow = tid >> 2;
    const int pcol = tid & 3;
    const int sgoff = ((pcol ^ (srow & 3)) << 4);       // global byte offset in BK
    const int sloff = srow * BK + (pcol << 4);          // LDS byte offset (== tid*16)

    // precomputed swizzled fragment offsets
    int aoff[2][2], boff[2][2];
#pragma unroll
    for (int i = 0; i < 2; ++i)
#pragma unroll
        for (int ks = 0; ks < 2; ++ks) {
            const int Ra = wm * 64 + i * 32 + ml;
            aoff[i][ks] = Ra * BK + (((ks * 2 + kh) ^ (Ra & 3)) << 4);
            const int Rb = wn * 64 + i * 32 + ml;
            boff[i][ks] = Rb * BK + (((ks * 2 + kh) ^ (Rb & 3)) << 4);
        }

    i32x16 acc[2][2] = {};

    for (int k0 = 0; k0 < K; k0 += BK) {
        gload_lds16(Ag + (size_t)srow * K + (k0 + sgoff), &As[sloff]);
        gload_lds16(Ag + (size_t)(srow + 64) * K + (k0 + sgoff), &As[64 * BK + sloff]);
        gload_lds16(Bg + (size_t)srow * K + (k0 + sgoff), &Bs[sloff]);
        gload_lds16(Bg + (size_t)(srow + 64) * K + (k0 + sgoff), &Bs[64 * BK + sloff]);
        __syncthreads();

        i32x4 af[2][2], bf[2][2];
#pragma unroll
        for (int i = 0; i < 2; ++i)
#pragma unroll
            for (int ks = 0; ks < 2; ++ks) {
                af[i][ks] = *(const i32x4*)&As[aoff[i][ks]];
                bf[i][ks] = *(const i32x4*)&Bs[boff[i][ks]];
            }

#pragma unroll
        for (int ks = 0; ks < 2; ++ks)
#pragma unroll
            for (int i = 0; i < 2; ++i)
#pragma unroll
                for (int j = 0; j < 2; ++j)
                    acc[i][j] = __builtin_amdgcn_mfma_i32_32x32x32_i8(
                        af[i][ks], bf[j][ks], acc[i][j], 0, 0, 0);

        __syncthreads();
    }

    // epilogue. 32x32 C/D layout: col = lane&31, row = (reg&3) + 8*(reg>>2) + 4*(lane>>5)
    int nidx[2], rsumn[2];
    float rsn[2], bsn[2];
#pragma unroll
    for (int j = 0; j < 2; ++j) {
        const int n = bn + wn * 64 + j * 32 + ml;
        nidx[j] = n; rsn[j] = rs[n]; rsumn[j] = rsum[n]; bsn[j] = bias[n];
    }
#pragma unroll
    for (int i = 0; i < 2; ++i)
#pragma unroll
        for (int r = 0; r < 16; ++r) {
            const int m = bm + wm * 64 + i * 32 + (r & 3) + 8 * (r >> 2) + 4 * kh;
            const float csm = cs[m];
            const int az = azp[m];
            float* yrow = Y + (size_t)m * N;
#pragma unroll
            for (int j = 0; j < 2; ++j) {
                const int tot = acc[i][j][r] + az * rsumn[j];
                yrow[nidx[j]] = fmaf((float)tot, csm * rsn[j], bsn[j]);
            }
        }
}

// ---------------- launch ----------------
extern "C" void kernel_launch(void* const* d_in, const int* in_sizes, int n_in,
                              void* d_out, int out_size, void* d_ws, size_t ws_size,
                              hipStream_t stream) {
    const float* x = (const float*)d_in[0];
    const float* w = (const float*)d_in[1];
    const float* bias = (const float*)d_in[2];
    float* y = (float*)d_out;

    const int N = in_sizes[2];            // 4096
    const int K = in_sizes[1] / N;        // 4096
    const int M = in_sizes[0] / K;        // 8192

    uint8_t* ws = (uint8_t*)d_ws;
    int8_t* Wq = (int8_t*)ws;                                  // N*K   int8
    int8_t* Xq = (int8_t*)(ws + (size_t)N * K);                // M*K   int8
    uint8_t* p = ws + (size_t)N * K + (size_t)M * K;
    p = (uint8_t*)(((uintptr_t)p + 255) & ~(uintptr_t)255);
    float* rscale = (float*)p;  p += (size_t)N * sizeof(float);
    int*   rsum   = (int*)p;    p += (size_t)N * sizeof(int);
    float* cscale = (float*)p;  p += (size_t)M * sizeof(float);
    int*   azp    = (int*)p;    p += (size_t)M * sizeof(int);

    const int NBW = (N + 3) / 4;
    const int NBA = (M + 3) / 4;
    quant_kernel<<<NBW + NBA, 256, 0, stream>>>(w, x, Wq, Xq, rscale, rsum,
                                                cscale, azp, K, N, M, NBW);

    dim3 grid(M / BM, N / BN);
    gemm_i8_kernel<<<grid, 256, 0, stream>>>(Xq, Wq, y, cscale, azp,
                                             rscale, rsum, bias, M, N, K);
}